// Round 4
// baseline (198.148 us; speedup 1.0000x reference)
//
#include <hip/hip_runtime.h>
#include <hip/hip_bf16.h>
#include <stdint.h>

typedef __bf16 bf16x8 __attribute__((ext_vector_type(8)));
typedef float f32x4 __attribute__((ext_vector_type(4)));
typedef unsigned short ushort_t;

// Shapes: B=2, S=2048, D=1024, H=16, HD=64.  M = B*S = 4096.

__device__ inline ushort_t f2bf(float f) {
  union { float f; uint32_t u; } v; v.f = f;
  uint32_t r = (v.u + 0x7fffu + ((v.u >> 16) & 1u)) >> 16;  // RNE
  return (ushort_t)r;
}

// async global->LDS, 16B per lane. LDS dest must be wave-uniform base + lane*16.
__device__ inline void gll16(const void* g, void* l) {
  __builtin_amdgcn_global_load_lds((const __attribute__((address_space(1))) void*)g,
                                   (__attribute__((address_space(3))) void*)l, 16, 0, 0);
}

// ---------------- converts ----------------
__global__ void cvt_x(const float* __restrict__ in, ushort_t* __restrict__ out) {
  int i = blockIdx.x * blockDim.x + threadIdx.x;  // 1M threads, 4 floats each
  float4 f = ((const float4*)in)[i];
  union { ushort_t u[4]; uint2 v; } r;
  r.u[0] = f2bf(f.x); r.u[1] = f2bf(f.y); r.u[2] = f2bf(f.z); r.u[3] = f2bf(f.w);
  ((uint2*)out)[i] = r.v;
}
__global__ void cvt_w(const float* __restrict__ a, const float* __restrict__ b,
                      const float* __restrict__ c, const float* __restrict__ d,
                      ushort_t* __restrict__ out) {
  const float* srcs[4] = {a, b, c, d};
  const float* s = srcs[blockIdx.y];
  ushort_t* o = out + (size_t)blockIdx.y * 1048576;
  int i = blockIdx.x * blockDim.x + threadIdx.x;
  float4 f = ((const float4*)s)[i];
  union { ushort_t u[4]; uint2 v; } r;
  r.u[0] = f2bf(f.x); r.u[1] = f2bf(f.y); r.u[2] = f2bf(f.z); r.u[3] = f2bf(f.w);
  ((uint2*)(o))[i] = r.v;
}

// ---------------- QKV projection (NT GEMM, bf16 in, bf16 out) -------------
// 128x128 tile, BK=32, 4 waves (2x2), 4x4 MFMA tiles each; global_load_lds staging (m97).
// z=0: q = X@Wq^T -> [B,H,S,HD] scaled by 0.125*log2(e)
// z=1: k = X@Wk^T -> [B,H,S,HD]
// z=2: OPERAND-SWAPPED: computes V^T = Wv @ X^T directly (A=Wv rows p, B=X rows tok),
//      so vto[B,H,HD,S] epilogue stores are lane-consecutive in s (coalesced 32B runs)
//      instead of 2B scatter at 4KB stride.
__global__ __launch_bounds__(256) void qkv_gemm(
    const ushort_t* __restrict__ xb,
    const ushort_t* __restrict__ qwb, const ushort_t* __restrict__ kwb, const ushort_t* __restrict__ vwb,
    const float* __restrict__ qbias, const float* __restrict__ kbias, const float* __restrict__ vbias,
    ushort_t* __restrict__ qo, ushort_t* __restrict__ ko, ushort_t* __restrict__ vto)
{
  const int z = blockIdx.z;
  const float* bias = (z == 0) ? qbias : (z == 1) ? kbias : vbias;
  const ushort_t* Ap;
  const ushort_t* Bp;
  int m0, n0;
  if (z == 2) {
    Ap = vwb; Bp = xb;
    m0 = blockIdx.x * 128;   // p = h*64+hd  in [0,1024)
    n0 = blockIdx.y * 128;   // tok = b*2048+s in [0,4096)
  } else {
    Ap = xb; Bp = (z == 0) ? qwb : kwb;
    m0 = blockIdx.y * 128;   // tok
    n0 = blockIdx.x * 128;   // feature
  }

  __shared__ __align__(16) ushort_t As[128 * 32];
  __shared__ __align__(16) ushort_t Bs[128 * 32];

  const int tid = threadIdx.x;
  const int w = tid >> 6;
  const int lane = tid & 63;
  const int ln = lane & 15;
  const int q4 = lane >> 4;
  const int wm = w & 1, wn = w >> 1;

  f32x4 acc[4][4];
  #pragma unroll
  for (int i = 0; i < 4; i++)
    #pragma unroll
    for (int j = 0; j < 4; j++) acc[i][j] = f32x4{0.f, 0.f, 0.f, 0.f};

  for (int k0 = 0; k0 < 1024; k0 += 32) {
    __syncthreads();
    #pragma unroll
    for (int i = 0; i < 2; i++) {
      int c = tid + i * 256;
      int row = c >> 2, cq = c & 3;
      gll16(&Ap[(size_t)(m0 + row) * 1024 + k0 + cq * 8], &As[c * 8]);
      gll16(&Bp[(size_t)(n0 + row) * 1024 + k0 + cq * 8], &Bs[c * 8]);
    }
    __syncthreads();
    bf16x8 af[4], bfr[4];
    #pragma unroll
    for (int t = 0; t < 4; t++) {
      af[t]  = *(const bf16x8*)(&As[(wm * 64 + t * 16 + ln) * 32 + q4 * 8]);
      bfr[t] = *(const bf16x8*)(&Bs[(wn * 64 + t * 16 + ln) * 32 + q4 * 8]);
    }
    #pragma unroll
    for (int tm = 0; tm < 4; tm++)
      #pragma unroll
      for (int tn = 0; tn < 4; tn++)
        acc[tm][tn] = __builtin_amdgcn_mfma_f32_16x16x32_bf16(af[tm], bfr[tn], acc[tm][tn], 0, 0, 0);
  }

  if (z == 2) {
    // C[p][tok]: row = p (bias index!), col = token. vto addr = b*2097152 + p*2048 + s.
    #pragma unroll
    for (int tn = 0; tn < 4; tn++) {
      int col = n0 + wn * 64 + tn * 16 + ln;   // token
      int bb = col >> 11, s = col & 2047;
      size_t base = (size_t)bb * 2097152 + s;
      #pragma unroll
      for (int tm = 0; tm < 4; tm++) {
        int prow = m0 + wm * 64 + tm * 16 + q4 * 4;
        #pragma unroll
        for (int r = 0; r < 4; r++) {
          int p = prow + r;
          vto[base + (size_t)p * 2048] = f2bf(acc[tm][tn][r] + bias[p]);
        }
      }
    }
  } else {
    #pragma unroll
    for (int tn = 0; tn < 4; tn++) {
      int col = n0 + wn * 64 + tn * 16 + ln;
      float bv = bias[col];
      int h = col >> 6, hd = col & 63;
      #pragma unroll
      for (int tm = 0; tm < 4; tm++) {
        int rowb = m0 + wm * 64 + tm * 16 + q4 * 4;
        #pragma unroll
        for (int r = 0; r < 4; r++) {
          int row = rowb + r;
          int b = row >> 11, s = row & 2047;
          float val = acc[tm][tn][r] + bv;
          if (z == 0) {
            qo[((size_t)((b * 16 + h) * 2048 + s)) * 64 + hd] = f2bf(val * 0.180336884f);
          } else {
            ko[((size_t)((b * 16 + h) * 2048 + s)) * 64 + hd] = f2bf(val);
          }
        }
      }
    }
  }
}

// ---------------- Flash attention ----------------
// BQ=128 per block (4 waves x 2 strips of 16 q-rows), BKV=64. Grid (16,32).
// Mirrored qt pairing: blocks id and id+256 (same CU under round-robin) get qt and 15-qt
// -> every CU pair sums to exactly 36 KV-tile iterations.
// Each staged K/V tile serves 128 q-rows; kf/vf LDS fragments reused across both strips
// (1.5x less LDS traffic per q-row vs BQ=64). Fixed-max softmax, l via ones-MFMA,
// exp folded into Q scale (0.125*log2e) -> raw v_exp_f32.
#define PAD 72
__global__ __launch_bounds__(256) void attn(
    const ushort_t* __restrict__ qp, const ushort_t* __restrict__ kp,
    const ushort_t* __restrict__ vtp, ushort_t* __restrict__ op)
{
  __shared__ __align__(16) ushort_t Ks[64 * PAD];
  __shared__ __align__(16) ushort_t Vts[64 * PAD];
  __shared__ __align__(16) ushort_t Ps[8][16 * PAD];

  const int tid = threadIdx.x;
  const int w = tid >> 6;
  const int lane = tid & 63;
  const int ln = lane & 15;
  const int q4 = lane >> 4;
  const int bh = blockIdx.y;
  const int b = bh >> 4, h = bh & 15;
  int tswz = (blockIdx.x + blockIdx.y) & 15;
  const int qt = (blockIdx.y & 16) ? (15 - tswz) : tswz;  // mirrored pairing
  const int q0 = qt * 128;
  const int nt = 2 * qt + 2;

  const int c0 = tid, c1 = tid + 256;  // 16B-chunk indices this thread stages
  const int kr0_row = c0 >> 3, kr0_col = (c0 & 7) * 8;
  const int kr1_row = c1 >> 3, kr1_col = (c1 & 7) * 8;

  bf16x8 onesf;
  {
    union { ushort_t u[8]; bf16x8 v; } t;
    #pragma unroll
    for (int j = 0; j < 8; j++) t.u[j] = 0x3F80;  // bf16 1.0
    onesf = t.v;
  }

  // Q fragments: 2 strips per wave, rows q0 + w*32 + s*16 + [0,16)
  bf16x8 qf[2][2];
  #pragma unroll
  for (int s = 0; s < 2; s++) {
    const ushort_t* base = qp + ((size_t)bh * 2048 + q0 + w * 32 + s * 16 + ln) * 64 + q4 * 8;
    qf[s][0] = *(const bf16x8*)(base);
    qf[s][1] = *(const bf16x8*)(base + 32);
  }

  f32x4 acc_o[2][4];
  f32x4 acc_l[2];
  #pragma unroll
  for (int s = 0; s < 2; s++) {
    acc_l[s] = f32x4{0.f, 0.f, 0.f, 0.f};
    #pragma unroll
    for (int t = 0; t < 4; t++) acc_o[s][t] = f32x4{0.f, 0.f, 0.f, 0.f};
  }

  // prologue: prefetch tile 0 into registers
  uint4 kr0, kr1, vr0, vr1;
  {
    const ushort_t* kb = kp + (size_t)bh * 2048 * 64;
    kr0 = *(const uint4*)(kb + kr0_row * 64 + kr0_col);
    kr1 = *(const uint4*)(kb + kr1_row * 64 + kr1_col);
    const ushort_t* vb = vtp + (size_t)bh * 64 * 2048;
    vr0 = *(const uint4*)(vb + (size_t)kr0_row * 2048 + kr0_col);
    vr1 = *(const uint4*)(vb + (size_t)kr1_row * 2048 + kr1_col);
  }

  for (int it = 0; it < nt; it++) {
    if (it) __syncthreads();  // all waves done reading LDS from prev iter
    *(uint4*)(&Ks [kr0_row * PAD + kr0_col]) = kr0;
    *(uint4*)(&Ks [kr1_row * PAD + kr1_col]) = kr1;
    *(uint4*)(&Vts[kr0_row * PAD + kr0_col]) = vr0;
    *(uint4*)(&Vts[kr1_row * PAD + kr1_col]) = vr1;
    __syncthreads();

    // prefetch next tile into registers (hides global latency behind compute)
    if (it + 1 < nt) {
      int kv1 = (it + 1) * 64;
      const ushort_t* kb = kp + ((size_t)bh * 2048 + kv1) * 64;
      kr0 = *(const uint4*)(kb + kr0_row * 64 + kr0_col);
      kr1 = *(const uint4*)(kb + kr1_row * 64 + kr1_col);
      const ushort_t* vb = vtp + (size_t)bh * 64 * 2048;
      vr0 = *(const uint4*)(vb + (size_t)kr0_row * 2048 + kv1 + kr0_col);
      vr1 = *(const uint4*)(vb + (size_t)kr1_row * 2048 + kv1 + kr1_col);
    }

    // S = Q K^T : kf fragments read once, used by both strips
    f32x4 sc[2][4];
    #pragma unroll
    for (int s = 0; s < 2; s++)
      #pragma unroll
      for (int t = 0; t < 4; t++) sc[s][t] = f32x4{0.f, 0.f, 0.f, 0.f};
    #pragma unroll
    for (int ks = 0; ks < 2; ks++) {
      bf16x8 kf[4];
      #pragma unroll
      for (int tn = 0; tn < 4; tn++)
        kf[tn] = *(const bf16x8*)(&Ks[(tn * 16 + ln) * PAD + ks * 32 + q4 * 8]);
      #pragma unroll
      for (int s = 0; s < 2; s++)
        #pragma unroll
        for (int tn = 0; tn < 4; tn++)
          sc[s][tn] = __builtin_amdgcn_mfma_f32_16x16x32_bf16(qf[s][ks], kf[tn], sc[s][tn], 0, 0, 0);
    }
    // causal mask: only the last two tiles can have masked entries (wave-uniform branch)
    if (it >= 2 * qt) {
      int kv0 = it * 64;
      #pragma unroll
      for (int s = 0; s < 2; s++) {
        int qrow = q0 + w * 32 + s * 16 + q4 * 4;
        #pragma unroll
        for (int tn = 0; tn < 4; tn++) {
          int col = kv0 + tn * 16 + ln;
          #pragma unroll
          for (int r = 0; r < 4; r++)
            if (col > qrow + r) sc[s][tn][r] = -__builtin_inff();
        }
      }
    }
    // p = 2^s (fixed-max softmax; scores are O(1)). Truncating f2bf: bias cancels since
    // l sums the same bf16 P via MFMA.
    #pragma unroll
    for (int s = 0; s < 2; s++)
      #pragma unroll
      for (int tn = 0; tn < 4; tn++)
        #pragma unroll
        for (int r = 0; r < 4; r++) {
          float p = __builtin_amdgcn_exp2f(sc[s][tn][r]);
          Ps[w * 2 + s][(q4 * 4 + r) * PAD + tn * 16 + ln] = (ushort_t)(__float_as_uint(p) >> 16);
        }
    // O += P V ; l += P @ ones. vf fragments read once, used by both strips.
    #pragma unroll
    for (int ks = 0; ks < 2; ks++) {
      bf16x8 vf[4];
      #pragma unroll
      for (int tn = 0; tn < 4; tn++)
        vf[tn] = *(const bf16x8*)(&Vts[(tn * 16 + ln) * PAD + ks * 32 + q4 * 8]);
      #pragma unroll
      for (int s = 0; s < 2; s++) {
        bf16x8 pf = *(const bf16x8*)(&Ps[w * 2 + s][ln * PAD + ks * 32 + q4 * 8]);
        acc_l[s] = __builtin_amdgcn_mfma_f32_16x16x32_bf16(pf, onesf, acc_l[s], 0, 0, 0);
        #pragma unroll
        for (int tn = 0; tn < 4; tn++)
          acc_o[s][tn] = __builtin_amdgcn_mfma_f32_16x16x32_bf16(pf, vf[tn], acc_o[s][tn], 0, 0, 0);
      }
    }
  }

  // write O as [B,S,D] bf16
  #pragma unroll
  for (int s = 0; s < 2; s++) {
    float invl[4];
    #pragma unroll
    for (int r = 0; r < 4; r++) invl[r] = __builtin_amdgcn_rcpf(acc_l[s][r]);
    #pragma unroll
    for (int tn = 0; tn < 4; tn++)
      #pragma unroll
      for (int r = 0; r < 4; r++) {
        int row = q0 + w * 32 + s * 16 + q4 * 4 + r;
        op[((size_t)b * 2048 + row) * 1024 + h * 64 + tn * 16 + ln] =
            f2bf(acc_o[s][tn][r] * invl[r]);
      }
  }
}

// ---------------- Output projection: out = O @ ow^T + ob (fp32 out) ----------------
// BM=64, BN=128 -> grid (8,64) = 512 blocks (2/CU). 4 waves as 2x2, wave tile 32x64.
__global__ __launch_bounds__(256) void out_gemm(
    const ushort_t* __restrict__ ob_in, const ushort_t* __restrict__ owb,
    const float* __restrict__ obias, float* __restrict__ out)
{
  __shared__ __align__(16) ushort_t As[64 * 32];
  __shared__ __align__(16) ushort_t Bs[128 * 32];

  const int tid = threadIdx.x;
  const int w = tid >> 6;
  const int lane = tid & 63;
  const int ln = lane & 15;
  const int q4 = lane >> 4;
  const int wm = w & 1, wn = w >> 1;
  const int m0 = blockIdx.y * 64;
  const int n0 = blockIdx.x * 128;

  f32x4 acc[2][4];
  #pragma unroll
  for (int i = 0; i < 2; i++)
    #pragma unroll
    for (int j = 0; j < 4; j++) acc[i][j] = f32x4{0.f, 0.f, 0.f, 0.f};

  for (int k0 = 0; k0 < 1024; k0 += 32) {
    __syncthreads();
    {
      int rowA = tid >> 2, cqA = tid & 3;
      gll16(&ob_in[(size_t)(m0 + rowA) * 1024 + k0 + cqA * 8], &As[tid * 8]);
      gll16(&owb  [(size_t)(n0 + rowA) * 1024 + k0 + cqA * 8], &Bs[tid * 8]);
      int c2 = tid + 256;
      int rowB = c2 >> 2, cqB = c2 & 3;
      gll16(&owb  [(size_t)(n0 + rowB) * 1024 + k0 + cqB * 8], &Bs[c2 * 8]);
    }
    __syncthreads();
    bf16x8 af[2], bfr[4];
    #pragma unroll
    for (int t = 0; t < 2; t++)
      af[t] = *(const bf16x8*)(&As[(wm * 32 + t * 16 + ln) * 32 + q4 * 8]);
    #pragma unroll
    for (int t = 0; t < 4; t++)
      bfr[t] = *(const bf16x8*)(&Bs[(wn * 64 + t * 16 + ln) * 32 + q4 * 8]);
    #pragma unroll
    for (int tm = 0; tm < 2; tm++)
      #pragma unroll
      for (int tn = 0; tn < 4; tn++)
        acc[tm][tn] = __builtin_amdgcn_mfma_f32_16x16x32_bf16(af[tm], bfr[tn], acc[tm][tn], 0, 0, 0);
  }

  #pragma unroll
  for (int tn = 0; tn < 4; tn++) {
    int col = n0 + wn * 64 + tn * 16 + ln;
    float bv = obias[col];
    #pragma unroll
    for (int tm = 0; tm < 2; tm++) {
      int rowb = m0 + wm * 32 + tm * 16 + q4 * 4;
      #pragma unroll
      for (int r = 0; r < 4; r++)
        out[(size_t)(rowb + r) * 1024 + col] = acc[tm][tn][r] + bv;
    }
  }
}

extern "C" void kernel_launch(void* const* d_in, const int* in_sizes, int n_in,
                              void* d_out, int out_size, void* d_ws, size_t ws_size,
                              hipStream_t stream) {
  const float* x     = (const float*)d_in[0];
  const float* qw    = (const float*)d_in[1];
  const float* qb    = (const float*)d_in[2];
  const float* kw    = (const float*)d_in[3];
  const float* kb    = (const float*)d_in[4];
  const float* vw    = (const float*)d_in[5];
  const float* vb    = (const float*)d_in[6];
  const float* ow    = (const float*)d_in[7];
  const float* obias = (const float*)d_in[8];
  float* out = (float*)d_out;

  char* ws = (char*)d_ws;
  ushort_t* xb  = (ushort_t*)(ws);              // 4096x1024 bf16 = 8 MB
  ushort_t* wb  = (ushort_t*)(ws + 8388608);    // qw,kw,vw,ow bf16, 2 MB each
  ushort_t* qwb = wb;
  ushort_t* kwb = wb + 1048576;
  ushort_t* vwb = wb + 2097152;
  ushort_t* owb = wb + 3145728;
  ushort_t* qo  = (ushort_t*)(ws + 16777216);   // [B,H,S,HD] bf16 = 8 MB
  ushort_t* ko  = (ushort_t*)(ws + 25165824);
  ushort_t* vto = (ushort_t*)(ws + 33554432);   // [B,H,HD,S] bf16
  ushort_t* oo  = (ushort_t*)(ws + 41943040);   // [B,S,D] bf16

  cvt_x<<<dim3(4096), dim3(256), 0, stream>>>(x, xb);
  cvt_w<<<dim3(1024, 4), dim3(256), 0, stream>>>(qw, kw, vw, ow, wb);

  qkv_gemm<<<dim3(8, 32, 3), dim3(256), 0, stream>>>(xb, qwb, kwb, vwb, qb, kb, vb, qo, ko, vto);
  attn<<<dim3(16, 32), dim3(256), 0, stream>>>(qo, ko, vto, oo);
  out_gemm<<<dim3(8, 64), dim3(256), 0, stream>>>(oo, owb, obias, out);
}

// Round 5
// 192.207 us; speedup vs baseline: 1.0309x; 1.0309x over previous
//
#include <hip/hip_runtime.h>
#include <hip/hip_bf16.h>
#include <stdint.h>

typedef __bf16 bf16x8 __attribute__((ext_vector_type(8)));
typedef __bf16 bf16x4 __attribute__((ext_vector_type(4)));
typedef float f32x4 __attribute__((ext_vector_type(4)));
typedef unsigned short ushort_t;

// Shapes: B=2, S=2048, D=1024, H=16, HD=64.  M = B*S = 4096.

__device__ inline ushort_t f2bf(float f) {
  union { float f; uint32_t u; } v; v.f = f;
  uint32_t r = (v.u + 0x7fffu + ((v.u >> 16) & 1u)) >> 16;  // RNE
  return (ushort_t)r;
}

// async global->LDS, 16B per lane. LDS dest must be wave-uniform base + lane*16.
__device__ inline void gll16(const void* g, void* l) {
  __builtin_amdgcn_global_load_lds((const __attribute__((address_space(1))) void*)g,
                                   (__attribute__((address_space(3))) void*)l, 16, 0, 0);
}

// ---------------- converts ----------------
__global__ void cvt_x(const float* __restrict__ in, ushort_t* __restrict__ out) {
  int i = blockIdx.x * blockDim.x + threadIdx.x;  // 1M threads, 4 floats each
  float4 f = ((const float4*)in)[i];
  union { ushort_t u[4]; uint2 v; } r;
  r.u[0] = f2bf(f.x); r.u[1] = f2bf(f.y); r.u[2] = f2bf(f.z); r.u[3] = f2bf(f.w);
  ((uint2*)out)[i] = r.v;
}
__global__ void cvt_w(const float* __restrict__ a, const float* __restrict__ b,
                      const float* __restrict__ c, const float* __restrict__ d,
                      ushort_t* __restrict__ out) {
  const float* srcs[4] = {a, b, c, d};
  const float* s = srcs[blockIdx.y];
  ushort_t* o = out + (size_t)blockIdx.y * 1048576;
  int i = blockIdx.x * blockDim.x + threadIdx.x;
  float4 f = ((const float4*)s)[i];
  union { ushort_t u[4]; uint2 v; } r;
  r.u[0] = f2bf(f.x); r.u[1] = f2bf(f.y); r.u[2] = f2bf(f.z); r.u[3] = f2bf(f.w);
  ((uint2*)(o))[i] = r.v;
}

// ---------------- QKV projection (NT GEMM, bf16 in, bf16 out) -------------
// 128x128 tile, BK=64 (16 k-iters -> half the barrier drains), 4 waves (2x2), 4x4 MFMA
// tiles; gll16 staging with XOR chunk swizzle: LDS slot c holds global chunk
// (c&7)^(row&7) of row c>>3 -> staging writes lane-contiguous (conflict-free) AND
// fragment reads land 2-way (free, m136) instead of 8-way.
// z=0: q = X@Wq^T -> [B,H,S,HD] scaled by 0.125*log2(e)
// z=1: k = X@Wk^T -> [B,H,S,HD]
// z=2: operand-swapped V^T = Wv @ X^T -> vto[B,H,HD,S] with coalesced stores.
__global__ __launch_bounds__(256) void qkv_gemm(
    const ushort_t* __restrict__ xb,
    const ushort_t* __restrict__ qwb, const ushort_t* __restrict__ kwb, const ushort_t* __restrict__ vwb,
    const float* __restrict__ qbias, const float* __restrict__ kbias, const float* __restrict__ vbias,
    ushort_t* __restrict__ qo, ushort_t* __restrict__ ko, ushort_t* __restrict__ vto)
{
  const int z = blockIdx.z;
  const float* bias = (z == 0) ? qbias : (z == 1) ? kbias : vbias;
  const ushort_t* Ap;
  const ushort_t* Bp;
  int m0, n0;
  if (z == 2) {
    Ap = vwb; Bp = xb;
    m0 = blockIdx.x * 128;   // p = h*64+hd
    n0 = blockIdx.y * 128;   // tok
  } else {
    Ap = xb; Bp = (z == 0) ? qwb : kwb;
    m0 = blockIdx.y * 128;   // tok
    n0 = blockIdx.x * 128;   // feature
  }

  __shared__ __align__(16) ushort_t As[128 * 64];  // 16 KB
  __shared__ __align__(16) ushort_t Bs[128 * 64];  // 16 KB

  const int tid = threadIdx.x;
  const int w = tid >> 6;
  const int lane = tid & 63;
  const int ln = lane & 15;
  const int q4 = lane >> 4;
  const int wm = w & 1, wn = w >> 1;

  f32x4 acc[4][4];
  #pragma unroll
  for (int i = 0; i < 4; i++)
    #pragma unroll
    for (int j = 0; j < 4; j++) acc[i][j] = f32x4{0.f, 0.f, 0.f, 0.f};

  for (int k0 = 0; k0 < 1024; k0 += 64) {
    __syncthreads();
    #pragma unroll
    for (int i = 0; i < 4; i++) {
      int c = tid + i * 256;               // 1024 chunks of 16B per tile
      int row = c >> 3;
      int cq = (c & 7) ^ (row & 7);        // XOR swizzle
      gll16(&Ap[(size_t)(m0 + row) * 1024 + k0 + cq * 8], &As[c * 8]);
      gll16(&Bp[(size_t)(n0 + row) * 1024 + k0 + cq * 8], &Bs[c * 8]);
    }
    __syncthreads();
    #pragma unroll
    for (int ks = 0; ks < 2; ks++) {
      bf16x8 af[4], bfr[4];
      #pragma unroll
      for (int t = 0; t < 4; t++) {
        int rr = wm * 64 + t * 16 + ln;
        af[t]  = *(const bf16x8*)(&As[rr * 64 + (((ks * 4 + q4) ^ (rr & 7)) * 8)]);
        int rc = wn * 64 + t * 16 + ln;
        bfr[t] = *(const bf16x8*)(&Bs[rc * 64 + (((ks * 4 + q4) ^ (rc & 7)) * 8)]);
      }
      #pragma unroll
      for (int tm = 0; tm < 4; tm++)
        #pragma unroll
        for (int tn = 0; tn < 4; tn++)
          acc[tm][tn] = __builtin_amdgcn_mfma_f32_16x16x32_bf16(af[tm], bfr[tn], acc[tm][tn], 0, 0, 0);
    }
  }

  if (z == 2) {
    #pragma unroll
    for (int tn = 0; tn < 4; tn++) {
      int col = n0 + wn * 64 + tn * 16 + ln;   // token
      int bb = col >> 11, s = col & 2047;
      size_t base = (size_t)bb * 2097152 + s;
      #pragma unroll
      for (int tm = 0; tm < 4; tm++) {
        int prow = m0 + wm * 64 + tm * 16 + q4 * 4;
        #pragma unroll
        for (int r = 0; r < 4; r++) {
          int p = prow + r;
          vto[base + (size_t)p * 2048] = f2bf(acc[tm][tn][r] + bias[p]);
        }
      }
    }
  } else {
    #pragma unroll
    for (int tn = 0; tn < 4; tn++) {
      int col = n0 + wn * 64 + tn * 16 + ln;
      float bv = bias[col];
      int h = col >> 6, hd = col & 63;
      #pragma unroll
      for (int tm = 0; tm < 4; tm++) {
        int rowb = m0 + wm * 64 + tm * 16 + q4 * 4;
        #pragma unroll
        for (int r = 0; r < 4; r++) {
          int row = rowb + r;
          int b = row >> 11, s = row & 2047;
          float val = acc[tm][tn][r] + bv;
          if (z == 0) {
            qo[((size_t)((b * 16 + h) * 2048 + s)) * 64 + hd] = f2bf(val * 0.180336884f);
          } else {
            ko[((size_t)((b * 16 + h) * 2048 + s)) * 64 + hd] = f2bf(val);
          }
        }
      }
    }
  }
}

// ---------------- Flash attention ----------------
// BQ=128 per block (4 waves x 2 strips), BKV=64. Grid (16,32), mirrored qt pairing.
// K/V PAD=72 (reads 2-way free, uint4 writes conflict-free). Ps stride 68 (136B):
// scalar b16 writes spread over all 32 banks (was 4-way at 72); reads via 8B-aligned
// b64 pairs (2-way, free). Fixed-max softmax, l via ones-MFMA, exp2-folded Q scale.
#define PAD 72
#define PPAD 68
__global__ __launch_bounds__(256) void attn(
    const ushort_t* __restrict__ qp, const ushort_t* __restrict__ kp,
    const ushort_t* __restrict__ vtp, ushort_t* __restrict__ op)
{
  __shared__ __align__(16) ushort_t Ks[64 * PAD];
  __shared__ __align__(16) ushort_t Vts[64 * PAD];
  __shared__ __align__(16) ushort_t Ps[8][16 * PPAD];

  const int tid = threadIdx.x;
  const int w = tid >> 6;
  const int lane = tid & 63;
  const int ln = lane & 15;
  const int q4 = lane >> 4;
  const int bh = blockIdx.y;
  const int b = bh >> 4, h = bh & 15;
  int tswz = (blockIdx.x + blockIdx.y) & 15;
  const int qt = (blockIdx.y & 16) ? (15 - tswz) : tswz;  // mirrored pairing
  const int q0 = qt * 128;
  const int nt = 2 * qt + 2;

  const int c0 = tid, c1 = tid + 256;
  const int kr0_row = c0 >> 3, kr0_col = (c0 & 7) * 8;
  const int kr1_row = c1 >> 3, kr1_col = (c1 & 7) * 8;

  bf16x8 onesf;
  {
    union { ushort_t u[8]; bf16x8 v; } t;
    #pragma unroll
    for (int j = 0; j < 8; j++) t.u[j] = 0x3F80;  // bf16 1.0
    onesf = t.v;
  }

  // Q fragments: 2 strips per wave, rows q0 + w*32 + s*16 + [0,16)
  bf16x8 qf[2][2];
  #pragma unroll
  for (int s = 0; s < 2; s++) {
    const ushort_t* base = qp + ((size_t)bh * 2048 + q0 + w * 32 + s * 16 + ln) * 64 + q4 * 8;
    qf[s][0] = *(const bf16x8*)(base);
    qf[s][1] = *(const bf16x8*)(base + 32);
  }

  f32x4 acc_o[2][4];
  f32x4 acc_l[2];
  #pragma unroll
  for (int s = 0; s < 2; s++) {
    acc_l[s] = f32x4{0.f, 0.f, 0.f, 0.f};
    #pragma unroll
    for (int t = 0; t < 4; t++) acc_o[s][t] = f32x4{0.f, 0.f, 0.f, 0.f};
  }

  // prologue: prefetch tile 0 into registers
  uint4 kr0, kr1, vr0, vr1;
  {
    const ushort_t* kb = kp + (size_t)bh * 2048 * 64;
    kr0 = *(const uint4*)(kb + kr0_row * 64 + kr0_col);
    kr1 = *(const uint4*)(kb + kr1_row * 64 + kr1_col);
    const ushort_t* vb = vtp + (size_t)bh * 64 * 2048;
    vr0 = *(const uint4*)(vb + (size_t)kr0_row * 2048 + kr0_col);
    vr1 = *(const uint4*)(vb + (size_t)kr1_row * 2048 + kr1_col);
  }

  for (int it = 0; it < nt; it++) {
    if (it) __syncthreads();
    *(uint4*)(&Ks [kr0_row * PAD + kr0_col]) = kr0;
    *(uint4*)(&Ks [kr1_row * PAD + kr1_col]) = kr1;
    *(uint4*)(&Vts[kr0_row * PAD + kr0_col]) = vr0;
    *(uint4*)(&Vts[kr1_row * PAD + kr1_col]) = vr1;
    __syncthreads();

    if (it + 1 < nt) {
      int kv1 = (it + 1) * 64;
      const ushort_t* kb = kp + ((size_t)bh * 2048 + kv1) * 64;
      kr0 = *(const uint4*)(kb + kr0_row * 64 + kr0_col);
      kr1 = *(const uint4*)(kb + kr1_row * 64 + kr1_col);
      const ushort_t* vb = vtp + (size_t)bh * 64 * 2048;
      vr0 = *(const uint4*)(vb + (size_t)kr0_row * 2048 + kv1 + kr0_col);
      vr1 = *(const uint4*)(vb + (size_t)kr1_row * 2048 + kv1 + kr1_col);
    }

    // S = Q K^T : kf fragments read once, used by both strips
    f32x4 sc[2][4];
    #pragma unroll
    for (int s = 0; s < 2; s++)
      #pragma unroll
      for (int t = 0; t < 4; t++) sc[s][t] = f32x4{0.f, 0.f, 0.f, 0.f};
    #pragma unroll
    for (int ks = 0; ks < 2; ks++) {
      bf16x8 kf[4];
      #pragma unroll
      for (int tn = 0; tn < 4; tn++)
        kf[tn] = *(const bf16x8*)(&Ks[(tn * 16 + ln) * PAD + ks * 32 + q4 * 8]);
      #pragma unroll
      for (int s = 0; s < 2; s++)
        #pragma unroll
        for (int tn = 0; tn < 4; tn++)
          sc[s][tn] = __builtin_amdgcn_mfma_f32_16x16x32_bf16(qf[s][ks], kf[tn], sc[s][tn], 0, 0, 0);
    }
    // causal mask only on the final two tiles (wave-uniform branch)
    if (it >= 2 * qt) {
      int kv0 = it * 64;
      #pragma unroll
      for (int s = 0; s < 2; s++) {
        int qrow = q0 + w * 32 + s * 16 + q4 * 4;
        #pragma unroll
        for (int tn = 0; tn < 4; tn++) {
          int col = kv0 + tn * 16 + ln;
          #pragma unroll
          for (int r = 0; r < 4; r++)
            if (col > qrow + r) sc[s][tn][r] = -__builtin_inff();
        }
      }
    }
    // p = 2^s (fixed-max softmax; scores are O(1)). Truncating f2bf: bias cancels since
    // l sums the same bf16 P via MFMA.
    #pragma unroll
    for (int s = 0; s < 2; s++)
      #pragma unroll
      for (int tn = 0; tn < 4; tn++)
        #pragma unroll
        for (int r = 0; r < 4; r++) {
          float p = __builtin_amdgcn_exp2f(sc[s][tn][r]);
          Ps[w * 2 + s][(q4 * 4 + r) * PPAD + tn * 16 + ln] = (ushort_t)(__float_as_uint(p) >> 16);
        }
    // O += P V ; l += P @ ones. vf fragments read once, used by both strips.
    #pragma unroll
    for (int ks = 0; ks < 2; ks++) {
      bf16x8 vf[4];
      #pragma unroll
      for (int tn = 0; tn < 4; tn++)
        vf[tn] = *(const bf16x8*)(&Vts[(tn * 16 + ln) * PAD + ks * 32 + q4 * 8]);
      #pragma unroll
      for (int s = 0; s < 2; s++) {
        const ushort_t* pp = &Ps[w * 2 + s][ln * PPAD + ks * 32 + q4 * 8];  // 8B-aligned
        bf16x4 plo = *(const bf16x4*)(pp);
        bf16x4 phi = *(const bf16x4*)(pp + 4);
        bf16x8 pf = __builtin_shufflevector(plo, phi, 0, 1, 2, 3, 4, 5, 6, 7);
        acc_l[s] = __builtin_amdgcn_mfma_f32_16x16x32_bf16(pf, onesf, acc_l[s], 0, 0, 0);
        #pragma unroll
        for (int tn = 0; tn < 4; tn++)
          acc_o[s][tn] = __builtin_amdgcn_mfma_f32_16x16x32_bf16(pf, vf[tn], acc_o[s][tn], 0, 0, 0);
      }
    }
  }

  // write O as [B,S,D] bf16
  #pragma unroll
  for (int s = 0; s < 2; s++) {
    float invl[4];
    #pragma unroll
    for (int r = 0; r < 4; r++) invl[r] = __builtin_amdgcn_rcpf(acc_l[s][r]);
    #pragma unroll
    for (int tn = 0; tn < 4; tn++)
      #pragma unroll
      for (int r = 0; r < 4; r++) {
        int row = q0 + w * 32 + s * 16 + q4 * 4 + r;
        op[((size_t)b * 2048 + row) * 1024 + h * 64 + tn * 16 + ln] =
            f2bf(acc_o[s][tn][r] * invl[r]);
      }
  }
}

// ---------------- Output projection: out = O @ ow^T + ob (fp32 out) ----------------
// BM=64, BN=128, BK=64 -> grid (8,64) = 512 blocks (2/CU). XOR chunk swizzle staging.
__global__ __launch_bounds__(256) void out_gemm(
    const ushort_t* __restrict__ ob_in, const ushort_t* __restrict__ owb,
    const float* __restrict__ obias, float* __restrict__ out)
{
  __shared__ __align__(16) ushort_t As[64 * 64];    // 8 KB
  __shared__ __align__(16) ushort_t Bs[128 * 64];   // 16 KB

  const int tid = threadIdx.x;
  const int w = tid >> 6;
  const int lane = tid & 63;
  const int ln = lane & 15;
  const int q4 = lane >> 4;
  const int wm = w & 1, wn = w >> 1;
  const int m0 = blockIdx.y * 64;
  const int n0 = blockIdx.x * 128;

  f32x4 acc[2][4];
  #pragma unroll
  for (int i = 0; i < 2; i++)
    #pragma unroll
    for (int j = 0; j < 4; j++) acc[i][j] = f32x4{0.f, 0.f, 0.f, 0.f};

  for (int k0 = 0; k0 < 1024; k0 += 64) {
    __syncthreads();
    #pragma unroll
    for (int i = 0; i < 2; i++) {
      int c = tid + i * 256;               // A: 512 chunks
      int row = c >> 3;
      int cq = (c & 7) ^ (row & 7);
      gll16(&ob_in[(size_t)(m0 + row) * 1024 + k0 + cq * 8], &As[c * 8]);
    }
    #pragma unroll
    for (int i = 0; i < 4; i++) {
      int c = tid + i * 256;               // B: 1024 chunks
      int row = c >> 3;
      int cq = (c & 7) ^ (row & 7);
      gll16(&owb[(size_t)(n0 + row) * 1024 + k0 + cq * 8], &Bs[c * 8]);
    }
    __syncthreads();
    #pragma unroll
    for (int ks = 0; ks < 2; ks++) {
      bf16x8 af[2], bfr[4];
      #pragma unroll
      for (int t = 0; t < 2; t++) {
        int rr = wm * 32 + t * 16 + ln;
        af[t] = *(const bf16x8*)(&As[rr * 64 + (((ks * 4 + q4) ^ (rr & 7)) * 8)]);
      }
      #pragma unroll
      for (int t = 0; t < 4; t++) {
        int rc = wn * 64 + t * 16 + ln;
        bfr[t] = *(const bf16x8*)(&Bs[rc * 64 + (((ks * 4 + q4) ^ (rc & 7)) * 8)]);
      }
      #pragma unroll
      for (int tm = 0; tm < 2; tm++)
        #pragma unroll
        for (int tn = 0; tn < 4; tn++)
          acc[tm][tn] = __builtin_amdgcn_mfma_f32_16x16x32_bf16(af[tm], bfr[tn], acc[tm][tn], 0, 0, 0);
    }
  }

  #pragma unroll
  for (int tn = 0; tn < 4; tn++) {
    int col = n0 + wn * 64 + tn * 16 + ln;
    float bv = obias[col];
    #pragma unroll
    for (int tm = 0; tm < 2; tm++) {
      int rowb = m0 + wm * 32 + tm * 16 + q4 * 4;
      #pragma unroll
      for (int r = 0; r < 4; r++)
        out[(size_t)(rowb + r) * 1024 + col] = acc[tm][tn][r] + bv;
    }
  }
}

extern "C" void kernel_launch(void* const* d_in, const int* in_sizes, int n_in,
                              void* d_out, int out_size, void* d_ws, size_t ws_size,
                              hipStream_t stream) {
  const float* x     = (const float*)d_in[0];
  const float* qw    = (const float*)d_in[1];
  const float* qb    = (const float*)d_in[2];
  const float* kw    = (const float*)d_in[3];
  const float* kb    = (const float*)d_in[4];
  const float* vw    = (const float*)d_in[5];
  const float* vb    = (const float*)d_in[6];
  const float* ow    = (const float*)d_in[7];
  const float* obias = (const float*)d_in[8];
  float* out = (float*)d_out;

  char* ws = (char*)d_ws;
  ushort_t* xb  = (ushort_t*)(ws);              // 4096x1024 bf16 = 8 MB
  ushort_t* wb  = (ushort_t*)(ws + 8388608);    // qw,kw,vw,ow bf16, 2 MB each
  ushort_t* qwb = wb;
  ushort_t* kwb = wb + 1048576;
  ushort_t* vwb = wb + 2097152;
  ushort_t* owb = wb + 3145728;
  ushort_t* qo  = (ushort_t*)(ws + 16777216);   // [B,H,S,HD] bf16 = 8 MB
  ushort_t* ko  = (ushort_t*)(ws + 25165824);
  ushort_t* vto = (ushort_t*)(ws + 33554432);   // [B,H,HD,S] bf16
  ushort_t* oo  = (ushort_t*)(ws + 41943040);   // [B,S,D] bf16

  cvt_x<<<dim3(4096), dim3(256), 0, stream>>>(x, xb);
  cvt_w<<<dim3(1024, 4), dim3(256), 0, stream>>>(qw, kw, vw, ow, wb);

  qkv_gemm<<<dim3(8, 32, 3), dim3(256), 0, stream>>>(xb, qwb, kwb, vwb, qb, kb, vb, qo, ko, vto);
  attn<<<dim3(16, 32), dim3(256), 0, stream>>>(qo, ko, vto, oo);
  out_gemm<<<dim3(8, 64), dim3(256), 0, stream>>>(oo, owb, obias, out);
}